// Round 16
// baseline (2528.109 us; speedup 1.0000x reference)
//
#include <hip/hip_runtime.h>
#include <stdint.h>

#define DIMN 1024
#define SEQN 2048
#define BATCHN 2
#define NCHUNK 8
#define CHUNKSZ 256
#define VOCABN 32000
#define ROWS_PB 6016            // sum of padded nk per batch
#define PSTRIDE_B (256*ROWS_PB) // P elements per batch
#define LN_EPS 1e-5f

#define MBIG 4096
#define NBIG 32000
#define KBIG 1024

typedef unsigned short ushort_t;
typedef __attribute__((ext_vector_type(8))) __bf16 bf16x8;
typedef __attribute__((ext_vector_type(4))) float f32x4;

__device__ const int d_nk[8]   = {256,512,768,769,769,769,769,770};
__device__ const int d_np[8]   = {256,512,768,896,896,896,896,896};
__device__ const int d_koff[8] = {0,256,768,1536,2432,3328,4224,5120};

__device__ __forceinline__ ushort_t f2bu(float f) {
  union { float f; unsigned u; } v; v.f = f;
  unsigned r = v.u + 0x7FFFu + ((v.u >> 16) & 1u);
  return (ushort_t)(r >> 16);
}
__device__ __forceinline__ float b2f(ushort_t u) {
  union { unsigned u; float f; } v; v.u = ((unsigned)u) << 16; return v.f;
}

// pos in [0,SEQ) of gathered key j for chunk i (closed form of _cache_positions)
__device__ __forceinline__ int pos_of(int i, int j) {
  if (i <= 2) return j;
  if (i <= 6) return (j == 0) ? 0 : (i - 3) * 256 + 255 + j;
  return (j == 0) ? 0 : ((j == 1) ? 1024 : 1278 + j);
}

__device__ __forceinline__ void gload16(const void* g, void* l) {
  __builtin_amdgcn_global_load_lds((__attribute__((address_space(1))) void*)g,
                                   (__attribute__((address_space(3))) void*)l,
                                   16, 0, 0);
}

// ---------------------------------------------------------------------------
// Swizzled 128x128 m97 core (conflict-free, PMC-verified r7).
// ---------------------------------------------------------------------------
__device__ __forceinline__ void mma_core_s(const ushort_t* __restrict__ A,
                                           const ushort_t* __restrict__ Bt,
                                           int K, ushort_t* lA, ushort_t* lB,
                                           f32x4 acc[4][4], int tid) {
  const int lane = tid & 63;
  const int wr = (tid >> 7) & 1;
  const int wc = (tid >> 6) & 1;
  const int frow = lane & 15;
  const int lhi = lane >> 4;
  const int xk = (frow & 7) << 4;
  const size_t ldb = (size_t)K * 2;     // row stride in bytes
  for (int kt = 0; kt < K; kt += 64) {
#pragma unroll
    for (int t = 0; t < 4; ++t) {
      int cid = t * 256 + tid;                       // 16B chunk id 0..1023
      int row = cid >> 3;                            // 0..127
      int srcoff = ((cid & 7) * 16) ^ ((row & 7) << 4);
      gload16((const char*)A  + (size_t)row * ldb + (size_t)kt * 2 + srcoff,
              (char*)lA + cid * 16);
      gload16((const char*)Bt + (size_t)row * ldb + (size_t)kt * 2 + srcoff,
              (char*)lB + cid * 16);
    }
    __syncthreads();
#pragma unroll
    for (int kk = 0; kk < 2; ++kk) {
      bf16x8 af[4], bfr[4];
#pragma unroll
      for (int m = 0; m < 4; ++m) {
        int r = wr * 64 + m * 16 + frow;
        af[m] = *(const bf16x8*)((const char*)lA +
                 ((r * 128 + kk * 64 + lhi * 16) ^ xk));
      }
#pragma unroll
      for (int n = 0; n < 4; ++n) {
        int r = wc * 64 + n * 16 + frow;
        bfr[n] = *(const bf16x8*)((const char*)lB +
                  ((r * 128 + kk * 64 + lhi * 16) ^ xk));
      }
#pragma unroll
      for (int m = 0; m < 4; ++m)
#pragma unroll
        for (int n = 0; n < 4; ++n)
          acc[m][n] = __builtin_amdgcn_mfma_f32_16x16x32_bf16(af[m], bfr[n],
                                                              acc[m][n], 0, 0, 0);
    }
    __syncthreads();
  }
}

// ===========================================================================
// Vocab projection, 3-blocks/CU variant: identical to the r15-validated
// 256x128 / BK=32 kernel (56 VGPR, 48 KiB LDS); only launch_bounds raised
// to 6 waves/EU so 3 blocks co-reside per CU (LDS 144/160 KiB, VGPR 56<=85).
// ===========================================================================
__global__ __launch_bounds__(512, 6) void k_vocab2(
    const ushort_t* __restrict__ A, const ushort_t* __restrict__ Bt,
    const float* __restrict__ bias, float* __restrict__ C) {
  __shared__ ushort_t lds[2][12288];   // per buf: A 16 KB | B 8 KB
  const int tid = threadIdx.x;
  const int lane = tid & 63, w = tid >> 6;   // 8 waves
  const int wm = w >> 1, wn = w & 1;         // 4 M-quarters x 2 N-halves
  const int frow = lane & 15, lhi = lane >> 4;

  // nt-fastest XCD mapping: 4000 blocks = 8 xcd x (2 mt x 250 nt)
  int l = blockIdx.x;
  int loc = l >> 3;                    // 0..499
  int mh = loc / 250;                  // 0..1
  const int mt = (l & 7) * 2 + mh;     // 0..15
  const int nt = loc - mh * 250;       // 0..249

  // staging: 3 x 16B chunks per thread per tile; linear LDS dest,
  // inverse-swizzled source.
  const char* srcs[3];
  int dsts[3];
  {
    const char* Ab = (const char*)(A + (size_t)mt * 256 * KBIG);
    const char* Bb = (const char*)(Bt + (size_t)nt * 128 * KBIG);
#pragma unroll
    for (int j = 0; j < 3; ++j) {
      int c = j * 512 + tid;           // 0..1535
      int isB = (c >= 1024) ? 1 : 0;
      int g = c - isB * 1024;          // chunk within operand
      int pr = g >> 3, cp = g & 7;
      int lc = cp ^ (pr & 7);          // logical chunk within pseudo-row
      int r  = pr * 2 + (lc >> 2);     // logical row
      int kc = lc & 3;                 // k-chunk 0..3 (8 bf16 each)
      srcs[j] = (isB ? Bb : Ab) + (size_t)r * 2048 + kc * 16;
      dsts[j] = isB * 16384 + g * 16;
    }
  }

  // read offsets (bytes): row r -> pseudo-row r>>1, chunk (r&1)*4 + lhi
  int aOff[4], bOff[4];
#pragma unroll
  for (int m = 0; m < 4; ++m) {
    int r = wm * 64 + m * 16 + frow;
    int pr = r >> 1, cc = (r & 1) * 4 + lhi;
    aOff[m] = pr * 128 + ((cc * 16) ^ ((pr & 7) << 4));
  }
#pragma unroll
  for (int n = 0; n < 4; ++n) {
    int r = wn * 64 + n * 16 + frow;
    int pr = r >> 1, cc = (r & 1) * 4 + lhi;
    bOff[n] = 16384 + pr * 128 + ((cc * 16) ^ ((pr & 7) << 4));
  }

  f32x4 acc[4][4] = {};

#define STG2(buf_, t_)                                                   \
  { char* d_ = (char*)&lds[buf_][0];                                     \
    _Pragma("unroll")                                                    \
    for (int j_ = 0; j_ < 3; ++j_)                                       \
      gload16(srcs[j_] + (size_t)(t_) * 64, d_ + dsts[j_]); }

  STG2(0, 0);
  for (int t = 0; t < 32; ++t) {       // 32 K-tiles of BK=32
    const int cur = t & 1;
    __builtin_amdgcn_sched_barrier(0);
    if (t + 1 < 32) {
      STG2(cur ^ 1, t + 1);
      asm volatile("s_waitcnt vmcnt(3)");  // oldest 3 = tile t landed
    } else {
      asm volatile("s_waitcnt vmcnt(0)");
    }
    __builtin_amdgcn_s_barrier();
    __builtin_amdgcn_sched_barrier(0);
    const char* bufp = (const char*)&lds[cur][0];
    bf16x8 aF[4], bF[4];
#pragma unroll
    for (int n = 0; n < 4; ++n) bF[n] = *(const bf16x8*)(bufp + bOff[n]);
#pragma unroll
    for (int m = 0; m < 4; ++m) aF[m] = *(const bf16x8*)(bufp + aOff[m]);
    __builtin_amdgcn_s_setprio(1);
#pragma unroll
    for (int m = 0; m < 4; ++m)
#pragma unroll
      for (int n = 0; n < 4; ++n)
        acc[m][n] = __builtin_amdgcn_mfma_f32_16x16x32_bf16(aF[m], bF[n],
                                                            acc[m][n], 0, 0, 0);
    __builtin_amdgcn_s_setprio(0);
    __builtin_amdgcn_s_barrier();
  }
#undef STG2

  const int rbase = mt * 256 + wm * 64 + lhi * 4;
  const int cbase = nt * 128 + wn * 64 + frow;
#pragma unroll
  for (int n = 0; n < 4; ++n) {
    float bv = bias[cbase + n * 16];
#pragma unroll
    for (int m = 0; m < 4; ++m)
#pragma unroll
      for (int j = 0; j < 4; ++j)
        __builtin_nontemporal_store(acc[m][n][j] + bv,
            &C[(size_t)(rbase + m * 16 + j) * NBIG + cbase + n * 16]);
  }
}

// ---------------------------------------------------------------------------
// One-shot weight conversion: qw|kw|vw -> wqkvb (packed), ow -> wob,
// outw -> woutb.  Grid-stride over float4s with segment routing.
// ---------------------------------------------------------------------------
#define SEG (DIMN*DIMN/4)        // 262144 float4 per square weight
__global__ __launch_bounds__(256) void k_cvt5(
    const float* __restrict__ qw, const float* __restrict__ kw,
    const float* __restrict__ vw, const float* __restrict__ ow,
    const float* __restrict__ outw, ushort_t* __restrict__ wqkvb,
    ushort_t* __restrict__ wob, ushort_t* __restrict__ woutb) {
  const int total = 4 * SEG + (VOCABN * DIMN / 4);
  int idx = blockIdx.x * 256 + threadIdx.x;
  int stride = gridDim.x * 256;
  for (int i = idx; i < total; i += stride) {
    const float4* src; ushort4* dst;
    if (i < 3 * SEG) {
      src = (const float4*)(i < SEG ? qw : i < 2 * SEG ? kw : vw) +
            (i - (i < SEG ? 0 : i < 2 * SEG ? SEG : 2 * SEG));
      dst = (ushort4*)wqkvb + i;
    } else if (i < 4 * SEG) {
      src = (const float4*)ow + (i - 3 * SEG);
      dst = (ushort4*)wob + (i - 3 * SEG);
    } else {
      src = (const float4*)outw + (i - 4 * SEG);
      dst = (ushort4*)woutb + (i - 4 * SEG);
    }
    float4 v = *src;
    *dst = make_ushort4(f2bu(v.x), f2bu(v.y), f2bu(v.z), f2bu(v.w));
  }
}

// ctx[b,t] = sum_{o=0..3, t-o>=0} emb[x[b,t-o]]  -> bf16
__global__ __launch_bounds__(256) void k_embed(const int* __restrict__ x,
                                               const float* __restrict__ emb,
                                               ushort_t* __restrict__ ctxb) {
  const int t = blockIdx.x, b = blockIdx.y, tid = threadIdx.x;
  float4 s = make_float4(0.f, 0.f, 0.f, 0.f);
#pragma unroll
  for (int o = 0; o < 4; ++o) {
    if (t - o < 0) break;
    int tok = x[b * SEQN + t - o];
    float4 v = ((const float4*)(emb + (size_t)tok * DIMN))[tid];
    s.x += v.x; s.y += v.y; s.z += v.z; s.w += v.w;
  }
  ((ushort4*)(ctxb + ((size_t)(b * SEQN + t)) * DIMN))[tid] =
      make_ushort4(f2bu(s.x), f2bu(s.y), f2bu(s.z), f2bu(s.w));
}

// fused QKV: 1D grid 768 = 24 nt x 32 mt, XCD-chunked, m-fastest.
__global__ __launch_bounds__(256) void k_qkv(const ushort_t* __restrict__ A,
    const ushort_t* __restrict__ Bt, const float* __restrict__ qb2,
    const float* __restrict__ kb2, const float* __restrict__ vb2,
    ushort_t* __restrict__ Qb, ushort_t* __restrict__ Kb,
    ushort_t* __restrict__ Vb) {
  int l = blockIdx.x;
  int swz = (l & 7) * ((int)gridDim.x >> 3) + (l >> 3);  // 768 % 8 == 0
  const int mt = swz & 31;               // 32 m-tiles
  const int nt = swz >> 5;               // 0..23
  __shared__ __align__(16) ushort_t lA[128*64];
  __shared__ __align__(16) ushort_t lB[128*64];
  f32x4 acc[4][4] = {};
  const int tid = threadIdx.x;
  mma_core_s(A + (size_t)mt * 128 * KBIG,
             Bt + (size_t)nt * 128 * KBIG, KBIG, lA, lB, acc, tid);
  const int which = nt >> 3;             // 0:Q 1:K 2:V (wave-uniform)
  const int col0  = (nt & 7) * 128;
  ushort_t* Out = (which == 0) ? Qb : (which == 1) ? Kb : Vb;
  const float* Bv = (which == 0) ? qb2 : (which == 1) ? kb2 : vb2;
  const int lane = tid & 63, wr = (tid >> 7) & 1, wc = (tid >> 6) & 1;
  const int rbase = mt * 128 + wr * 64 + (lane >> 4) * 4;
  const int cbase = col0 + wc * 64 + (lane & 15);
#pragma unroll
  for (int m = 0; m < 4; ++m)
#pragma unroll
    for (int n = 0; n < 4; ++n) {
      int c = cbase + n * 16;
      float bv = Bv[c];
#pragma unroll
      for (int j = 0; j < 4; ++j)
        Out[(size_t)(rbase + m * 16 + j) * DIMN + c] = f2bu(acc[m][n][j] + bv);
    }
}

// o-proj: bf16 output (feeds LN)
__global__ __launch_bounds__(256) void k_oproj(const ushort_t* __restrict__ A,
    const ushort_t* __restrict__ Bt, const float* __restrict__ bias,
    ushort_t* __restrict__ C) {
  __shared__ __align__(16) ushort_t lA[128*64];
  __shared__ __align__(16) ushort_t lB[128*64];
  f32x4 acc[4][4] = {};
  const int tid = threadIdx.x;
  mma_core_s(A + (size_t)blockIdx.y * 128 * KBIG,
             Bt + (size_t)blockIdx.x * 128 * KBIG, KBIG, lA, lB, acc, tid);
  const int lane = tid & 63, wr = (tid >> 7) & 1, wc = (tid >> 6) & 1;
  const int rbase = blockIdx.y * 128 + wr * 64 + (lane >> 4) * 4;
  const int cbase = blockIdx.x * 128 + wc * 64 + (lane & 15);
#pragma unroll
  for (int m = 0; m < 4; ++m)
#pragma unroll
    for (int n = 0; n < 4; ++n) {
      int c = cbase + n * 16;
      float bv = bias[c];
#pragma unroll
      for (int j = 0; j < 4; ++j)
        C[(size_t)(rbase + m * 16 + j) * DIMN + c] = f2bu(acc[m][n][j] + bv);
    }
}

// transpose-gather V -> VgT[b][chunk]: [DIM][np] (zeros in pad)
__global__ __launch_bounds__(256) void k_transV(const ushort_t* __restrict__ Vb,
                                                ushort_t* __restrict__ VgT) {
  __shared__ ushort_t tile[64][66];
  const int z = blockIdx.z, b = z >> 3, i = z & 7;
  const int np = d_np[i], nk = d_nk[i], ko = d_koff[i];
  const int jb = blockIdx.x * 64;
  if (jb >= np) return;
  const int db = blockIdx.y * 64;
  const int tid = threadIdx.x, tx = tid & 63, ty = tid >> 6;
#pragma unroll
  for (int rep = 0; rep < 16; ++rep) {
    int jl = rep * 4 + ty;
    int j = jb + jl;
    ushort_t v = 0;
    if (j < nk) v = Vb[((size_t)b * SEQN + pos_of(i, j)) * DIMN + db + tx];
    tile[jl][tx] = v;
  }
  __syncthreads();
  const size_t base = ((size_t)b * ROWS_PB + ko) * DIMN;
#pragma unroll
  for (int rep = 0; rep < 16; ++rep) {
    int dl = rep * 4 + ty;
    VgT[base + (size_t)(db + dl) * np + jb + tx] = tile[tx][dl];
  }
}

// scores: P = exp(scale * Q K^T) with causal/pad mask -> bf16.
// K rows staged DIRECTLY from Kb via pos_of; per-row source pointers hoisted.
__global__ __launch_bounds__(256) void k_scores(const ushort_t* __restrict__ Qb,
    const ushort_t* __restrict__ Kb, ushort_t* __restrict__ P) {
  const int z = blockIdx.z, b = z >> 3, i = z & 7;
  const int np = d_np[i], nk = d_nk[i], ko = d_koff[i];
  if ((int)blockIdx.x * 128 >= np) return;
  __shared__ __align__(16) ushort_t lA[128*64];
  __shared__ __align__(16) ushort_t lB[128*64];
  f32x4 acc[4][4] = {};
  const int tid = threadIdx.x;
  const int lane = tid & 63, wr = (tid >> 7) & 1, wc = (tid >> 6) & 1;
  const int frow = lane & 15, lhi = lane >> 4;
  const int xk = (frow & 7) << 4;

  const char* sA[4]; const char* sB[4];
  {
    const char* Aq = (const char*)(Qb +
        ((size_t)(b * SEQN + i * CHUNKSZ) + blockIdx.y * 128) * DIMN);
#pragma unroll
    for (int t = 0; t < 4; ++t) {
      int cid = t * 256 + tid;
      int row = cid >> 3;                            // 0..127
      int srcoff = ((cid & 7) * 16) ^ ((row & 7) << 4);
      sA[t] = Aq + (size_t)row * 2048 + srcoff;
      int jg = blockIdx.x * 128 + row;               // gathered key index
      int pos = (jg < nk) ? pos_of(i, jg) : 0;       // pad -> row 0 (masked)
      sB[t] = (const char*)(Kb + ((size_t)b * SEQN + pos) * DIMN) + srcoff;
    }
  }

  for (int kt = 0; kt < KBIG; kt += 64) {
#pragma unroll
    for (int t = 0; t < 4; ++t) {
      int cid = t * 256 + tid;
      gload16(sA[t] + (size_t)kt * 2, (char*)lA + cid * 16);
      gload16(sB[t] + (size_t)kt * 2, (char*)lB + cid * 16);
    }
    __syncthreads();
#pragma unroll
    for (int kk = 0; kk < 2; ++kk) {
      bf16x8 af[4], bfr[4];
#pragma unroll
      for (int m = 0; m < 4; ++m) {
        int r = wr * 64 + m * 16 + frow;
        af[m] = *(const bf16x8*)((const char*)lA +
                 ((r * 128 + kk * 64 + lhi * 16) ^ xk));
      }
#pragma unroll
      for (int n = 0; n < 4; ++n) {
        int r = wc * 64 + n * 16 + frow;
        bfr[n] = *(const bf16x8*)((const char*)lB +
                  ((r * 128 + kk * 64 + lhi * 16) ^ xk));
      }
#pragma unroll
      for (int m = 0; m < 4; ++m)
#pragma unroll
        for (int n = 0; n < 4; ++n)
          acc[m][n] = __builtin_amdgcn_mfma_f32_16x16x32_bf16(af[m], bfr[n],
                                                              acc[m][n], 0, 0, 0);
    }
    __syncthreads();
  }

  const int rb = blockIdx.y * 128 + wr * 64 + (lane >> 4) * 4;
  const int cb = blockIdx.x * 128 + wc * 64 + (lane & 15);
  ushort_t* Pc = P + (size_t)b * PSTRIDE_B + (size_t)ko * 256;
  const float scale = 0.03125f;  // 1/sqrt(1024)
  const int diag0 = nk - CHUNKSZ;
#pragma unroll
  for (int m = 0; m < 4; ++m)
#pragma unroll
    for (int n = 0; n < 4; ++n) {
      int c = cb + n * 16;
#pragma unroll
      for (int j = 0; j < 4; ++j) {
        int r = rb + m * 16 + j;
        float w = 0.0f;
        if (c < nk && (c - diag0) <= r) w = expf(acc[m][n][j] * scale);
        Pc[(size_t)r * np + c] = f2bu(w);
      }
    }
}

// deterministic row sums of P (bf16 values, f32 accumulate)
__global__ __launch_bounds__(256) void k_rowsum(const ushort_t* __restrict__ P,
                                                float* __restrict__ rowsum) {
  const int z = blockIdx.y, b = z >> 3, i = z & 7, r = blockIdx.x;
  const int np = d_np[i], ko = d_koff[i];
  const ushort_t* row = P + (size_t)b * PSTRIDE_B + (size_t)ko * 256 + (size_t)r * np;
  const int tid = threadIdx.x;
  float s = 0.f;
  for (int c = tid; c < np; c += 256) s += b2f(row[c]);
#pragma unroll
  for (int o = 1; o < 64; o <<= 1) s += __shfl_xor(s, o);
  __shared__ float ss[4];
  if ((tid & 63) == 0) ss[tid >> 6] = s;
  __syncthreads();
  if (tid == 0) rowsum[z * 256 + r] = ss[0] + ss[1] + ss[2] + ss[3];
}

// attended = (P @ Vg) / rowsum -> bf16
__global__ __launch_bounds__(256) void k_pv(const ushort_t* __restrict__ P,
    const ushort_t* __restrict__ VgT, const float* __restrict__ rowsum,
    ushort_t* __restrict__ attb) {
  const int z = blockIdx.z, b = z >> 3, i = z & 7;
  const int np = d_np[i], ko = d_koff[i];
  __shared__ __align__(16) ushort_t lA[128*64];
  __shared__ __align__(16) ushort_t lB[128*64];
  f32x4 acc[4][4] = {};
  const int tid = threadIdx.x;
  const ushort_t* A  = P + (size_t)b * PSTRIDE_B + (size_t)ko * 256 +
                       (size_t)blockIdx.y * 128 * np;
  const ushort_t* Bt = VgT + ((size_t)b * ROWS_PB + ko) * DIMN +
                       (size_t)blockIdx.x * 128 * np;
  mma_core_s(A, Bt, np, lA, lB, acc, tid);
  const int lane = tid & 63, wr = (tid >> 7) & 1, wc = (tid >> 6) & 1;
  const int rb = blockIdx.y * 128 + wr * 64 + (lane >> 4) * 4;
  const int cb = blockIdx.x * 128 + wc * 64 + (lane & 15);
  const float* rs = rowsum + z * 256;
  ushort_t* outp = attb + (size_t)(b * SEQN + i * CHUNKSZ) * DIMN;
#pragma unroll
  for (int m = 0; m < 4; ++m)
#pragma unroll
    for (int j = 0; j < 4; ++j) {
      int r = rb + m * 16 + j;
      float inv = 1.0f / rs[r];
#pragma unroll
      for (int n = 0; n < 4; ++n)
        outp[(size_t)r * DIMN + cb + n * 16] = f2bu(acc[m][n][j] * inv);
    }
}

// LN over bf16 h -> bf16 hb
__global__ __launch_bounds__(256) void k_ln(const ushort_t* __restrict__ h,
    const float* __restrict__ lnw, const float* __restrict__ lnb,
    ushort_t* __restrict__ hb) {
  const int row = blockIdx.x, tid = threadIdx.x;
  ushort4 u4 = ((const ushort4*)(h + (size_t)row * DIMN))[tid];
  float4 v = make_float4(b2f(u4.x), b2f(u4.y), b2f(u4.z), b2f(u4.w));
  float s  = v.x + v.y + v.z + v.w;
  float sq = v.x * v.x + v.y * v.y + v.z * v.z + v.w * v.w;
#pragma unroll
  for (int o = 1; o < 64; o <<= 1) { s += __shfl_xor(s, o); sq += __shfl_xor(sq, o); }
  __shared__ float ss[4], ssq[4];
  if ((tid & 63) == 0) { ss[tid >> 6] = s; ssq[tid >> 6] = sq; }
  __syncthreads();
  s  = ss[0] + ss[1] + ss[2] + ss[3];
  sq = ssq[0] + ssq[1] + ssq[2] + ssq[3];
  const float mu  = s * (1.0f / DIMN);
  const float var = sq * (1.0f / DIMN) - mu * mu;
  const float inv = rsqrtf(var + LN_EPS);
  float4 w4 = ((const float4*)lnw)[tid];
  float4 b4 = ((const float4*)lnb)[tid];
  ushort4 o4 = make_ushort4(f2bu((v.x - mu) * inv * w4.x + b4.x),
                            f2bu((v.y - mu) * inv * w4.y + b4.y),
                            f2bu((v.z - mu) * inv * w4.z + b4.z),
                            f2bu((v.w - mu) * inv * w4.w + b4.w));
  ((ushort4*)(hb + (size_t)row * DIMN))[tid] = o4;
}

// ---------------------------------------------------------------------------
extern "C" void kernel_launch(void* const* d_in, const int* in_sizes, int n_in,
                              void* d_out, int out_size, void* d_ws, size_t ws_size,
                              hipStream_t stream) {
  const int*   x    = (const int*)  d_in[0];
  const float* emb  = (const float*)d_in[1];
  const float* qw   = (const float*)d_in[2];
  const float* qb   = (const float*)d_in[3];
  const float* kw   = (const float*)d_in[4];
  const float* kb   = (const float*)d_in[5];
  const float* vw   = (const float*)d_in[6];
  const float* vb   = (const float*)d_in[7];
  const float* ow   = (const float*)d_in[8];
  const float* ob   = (const float*)d_in[9];
  const float* lnw  = (const float*)d_in[10];
  const float* lnb  = (const float*)d_in[11];
  const float* outw = (const float*)d_in[12];
  const float* outb = (const float*)d_in[13];
  float* out = (float*)d_out;
  (void)in_sizes; (void)n_in; (void)out_size; (void)ws_size;

  char* ws = (char*)d_ws;
  size_t off = 0;
  auto alloc = [&](size_t bytes) {
    size_t r = off; off += (bytes + 255) & ~(size_t)255; return r;
  };
  ushort_t* wqkvb = (ushort_t*)(ws + alloc((size_t)3 * DIMN * DIMN * 2));
  ushort_t* wob   = (ushort_t*)(ws + alloc((size_t)DIMN * DIMN * 2));
  ushort_t* woutb = (ushort_t*)(ws + alloc((size_t)VOCABN * DIMN * 2));
  ushort_t* ctxb  = (ushort_t*)(ws + alloc((size_t)BATCHN * SEQN * DIMN * 2));
  ushort_t* Qb    = (ushort_t*)(ws + alloc((size_t)BATCHN * SEQN * DIMN * 2));
  ushort_t* Kb    = (ushort_t*)(ws + alloc((size_t)BATCHN * SEQN * DIMN * 2));
  ushort_t* Vb    = (ushort_t*)(ws + alloc((size_t)BATCHN * SEQN * DIMN * 2));
  ushort_t* VgT   = (ushort_t*)(ws + alloc((size_t)BATCHN * ROWS_PB * DIMN * 2));
  ushort_t* Pm    = (ushort_t*)(ws + alloc((size_t)BATCHN * PSTRIDE_B * 2));
  float*    rsum  = (float*)   (ws + alloc((size_t)BATCHN * NCHUNK * 256 * 4));
  ushort_t* attb  = (ushort_t*)(ws + alloc((size_t)BATCHN * SEQN * DIMN * 2));
  ushort_t* hbuf  = (ushort_t*)(ws + alloc((size_t)BATCHN * SEQN * DIMN * 2));
  ushort_t* hb    = (ushort_t*)(ws + alloc((size_t)BATCHN * SEQN * DIMN * 2));

  // all weight conversions in one launch
  k_cvt5<<<dim3(4096), dim3(256), 0, stream>>>(qw, kw, vw, ow, outw,
                                               wqkvb, wob, woutb);

  // embedding + 4-tap context sum
  k_embed<<<dim3(SEQN, BATCHN), dim3(256), 0, stream>>>(x, emb, ctxb);

  // fused QKV projection (768 blocks, XCD-chunked)
  k_qkv<<<dim3(768), dim3(256), 0, stream>>>(ctxb, wqkvb, qb, kb, vb,
                                             Qb, Kb, Vb);

  // V transpose-gather (K gather folded into k_scores)
  k_transV<<<dim3(14, 16, BATCHN * NCHUNK), dim3(256), 0, stream>>>(Vb, VgT);

  // attention
  k_scores<<<dim3(7, 2, BATCHN * NCHUNK), dim3(256), 0, stream>>>(Qb, Kb, Pm);
  k_rowsum<<<dim3(256, BATCHN * NCHUNK), dim3(256), 0, stream>>>(Pm, rsum);
  k_pv<<<dim3(8, 2, BATCHN * NCHUNK), dim3(256), 0, stream>>>(Pm, VgT, rsum, attb);

  // output projection (bf16 out) + layernorm (bf16 in)
  k_oproj<<<dim3(8, 32), dim3(256), 0, stream>>>(attb, wob, ob, hbuf);
  k_ln<<<dim3(BATCHN * SEQN), dim3(256), 0, stream>>>(hbuf, lnw, lnb, hb);

  // vocab projection: 256x128 / BK=32 / 3-blocks-per-CU kernel, 4000 blocks
  k_vocab2<<<dim3(4000), dim3(512), 0, stream>>>(hb, woutb, outb, out);
}

// Round 17
// 503.111 us; speedup vs baseline: 5.0249x; 5.0249x over previous
//
#include <hip/hip_runtime.h>
#include <stdint.h>

#define DIMN 1024
#define SEQN 2048
#define BATCHN 2
#define NCHUNK 8
#define CHUNKSZ 256
#define VOCABN 32000
#define ROWS_PB 6016            // sum of padded nk per batch
#define PSTRIDE_B (256*ROWS_PB) // P elements per batch
#define LN_EPS 1e-5f

#define MBIG 4096
#define NBIG 32000
#define KBIG 1024

typedef unsigned short ushort_t;
typedef __attribute__((ext_vector_type(8))) __bf16 bf16x8;
typedef __attribute__((ext_vector_type(4))) float f32x4;

__device__ const int d_nk[8]   = {256,512,768,769,769,769,769,770};
__device__ const int d_np[8]   = {256,512,768,896,896,896,896,896};
__device__ const int d_koff[8] = {0,256,768,1536,2432,3328,4224,5120};

__device__ __forceinline__ ushort_t f2bu(float f) {
  union { float f; unsigned u; } v; v.f = f;
  unsigned r = v.u + 0x7FFFu + ((v.u >> 16) & 1u);
  return (ushort_t)(r >> 16);
}
__device__ __forceinline__ float b2f(ushort_t u) {
  union { unsigned u; float f; } v; v.u = ((unsigned)u) << 16; return v.f;
}

// pos in [0,SEQ) of gathered key j for chunk i (closed form of _cache_positions)
__device__ __forceinline__ int pos_of(int i, int j) {
  if (i <= 2) return j;
  if (i <= 6) return (j == 0) ? 0 : (i - 3) * 256 + 255 + j;
  return (j == 0) ? 0 : ((j == 1) ? 1024 : 1278 + j);
}

__device__ __forceinline__ void gload16(const void* g, void* l) {
  __builtin_amdgcn_global_load_lds((__attribute__((address_space(1))) void*)g,
                                   (__attribute__((address_space(3))) void*)l,
                                   16, 0, 0);
}

// ---------------------------------------------------------------------------
// Swizzled 128x128 m97 core (conflict-free, PMC-verified r7).
// ---------------------------------------------------------------------------
__device__ __forceinline__ void mma_core_s(const ushort_t* __restrict__ A,
                                           const ushort_t* __restrict__ Bt,
                                           int K, ushort_t* lA, ushort_t* lB,
                                           f32x4 acc[4][4], int tid) {
  const int lane = tid & 63;
  const int wr = (tid >> 7) & 1;
  const int wc = (tid >> 6) & 1;
  const int frow = lane & 15;
  const int lhi = lane >> 4;
  const int xk = (frow & 7) << 4;
  const size_t ldb = (size_t)K * 2;     // row stride in bytes
  for (int kt = 0; kt < K; kt += 64) {
#pragma unroll
    for (int t = 0; t < 4; ++t) {
      int cid = t * 256 + tid;                       // 16B chunk id 0..1023
      int row = cid >> 3;                            // 0..127
      int srcoff = ((cid & 7) * 16) ^ ((row & 7) << 4);
      gload16((const char*)A  + (size_t)row * ldb + (size_t)kt * 2 + srcoff,
              (char*)lA + cid * 16);
      gload16((const char*)Bt + (size_t)row * ldb + (size_t)kt * 2 + srcoff,
              (char*)lB + cid * 16);
    }
    __syncthreads();
#pragma unroll
    for (int kk = 0; kk < 2; ++kk) {
      bf16x8 af[4], bfr[4];
#pragma unroll
      for (int m = 0; m < 4; ++m) {
        int r = wr * 64 + m * 16 + frow;
        af[m] = *(const bf16x8*)((const char*)lA +
                 ((r * 128 + kk * 64 + lhi * 16) ^ xk));
      }
#pragma unroll
      for (int n = 0; n < 4; ++n) {
        int r = wc * 64 + n * 16 + frow;
        bfr[n] = *(const bf16x8*)((const char*)lB +
                  ((r * 128 + kk * 64 + lhi * 16) ^ xk));
      }
#pragma unroll
      for (int m = 0; m < 4; ++m)
#pragma unroll
        for (int n = 0; n < 4; ++n)
          acc[m][n] = __builtin_amdgcn_mfma_f32_16x16x32_bf16(af[m], bfr[n],
                                                              acc[m][n], 0, 0, 0);
    }
    __syncthreads();
  }
}

// ===========================================================================
// Vocab projection (r15-exact validated, 327 us): 256x128 tile, BK=32,
// 8 waves of 64x64 (4x2), 48 KiB dbuf LDS, 56 VGPR at launch_bounds(512,4)
// -> 2 blocks/CU, zero spill.  PMC: 0 bank conflicts, Occ 40%, Mfma 35%.
// ===========================================================================
__global__ __launch_bounds__(512, 4) void k_vocab2(
    const ushort_t* __restrict__ A, const ushort_t* __restrict__ Bt,
    const float* __restrict__ bias, float* __restrict__ C) {
  __shared__ ushort_t lds[2][12288];   // per buf: A 16 KB | B 8 KB
  const int tid = threadIdx.x;
  const int lane = tid & 63, w = tid >> 6;   // 8 waves
  const int wm = w >> 1, wn = w & 1;         // 4 M-quarters x 2 N-halves
  const int frow = lane & 15, lhi = lane >> 4;

  // nt-fastest XCD mapping: 4000 blocks = 8 xcd x (2 mt x 250 nt)
  int l = blockIdx.x;
  int loc = l >> 3;                    // 0..499
  int mh = loc / 250;                  // 0..1
  const int mt = (l & 7) * 2 + mh;     // 0..15
  const int nt = loc - mh * 250;       // 0..249

  // staging: 3 x 16B chunks per thread per tile; linear LDS dest,
  // inverse-swizzled source.
  const char* srcs[3];
  int dsts[3];
  {
    const char* Ab = (const char*)(A + (size_t)mt * 256 * KBIG);
    const char* Bb = (const char*)(Bt + (size_t)nt * 128 * KBIG);
#pragma unroll
    for (int j = 0; j < 3; ++j) {
      int c = j * 512 + tid;           // 0..1535
      int isB = (c >= 1024) ? 1 : 0;
      int g = c - isB * 1024;          // chunk within operand
      int pr = g >> 3, cp = g & 7;
      int lc = cp ^ (pr & 7);          // logical chunk within pseudo-row
      int r  = pr * 2 + (lc >> 2);     // logical row
      int kc = lc & 3;                 // k-chunk 0..3 (8 bf16 each)
      srcs[j] = (isB ? Bb : Ab) + (size_t)r * 2048 + kc * 16;
      dsts[j] = isB * 16384 + g * 16;
    }
  }

  // read offsets (bytes): row r -> pseudo-row r>>1, chunk (r&1)*4 + lhi
  int aOff[4], bOff[4];
#pragma unroll
  for (int m = 0; m < 4; ++m) {
    int r = wm * 64 + m * 16 + frow;
    int pr = r >> 1, cc = (r & 1) * 4 + lhi;
    aOff[m] = pr * 128 + ((cc * 16) ^ ((pr & 7) << 4));
  }
#pragma unroll
  for (int n = 0; n < 4; ++n) {
    int r = wn * 64 + n * 16 + frow;
    int pr = r >> 1, cc = (r & 1) * 4 + lhi;
    bOff[n] = 16384 + pr * 128 + ((cc * 16) ^ ((pr & 7) << 4));
  }

  f32x4 acc[4][4] = {};

#define STG2(buf_, t_)                                                   \
  { char* d_ = (char*)&lds[buf_][0];                                     \
    _Pragma("unroll")                                                    \
    for (int j_ = 0; j_ < 3; ++j_)                                       \
      gload16(srcs[j_] + (size_t)(t_) * 64, d_ + dsts[j_]); }

  STG2(0, 0);
  for (int t = 0; t < 32; ++t) {       // 32 K-tiles of BK=32
    const int cur = t & 1;
    __builtin_amdgcn_sched_barrier(0);
    if (t + 1 < 32) {
      STG2(cur ^ 1, t + 1);
      asm volatile("s_waitcnt vmcnt(3)");  // oldest 3 = tile t landed
    } else {
      asm volatile("s_waitcnt vmcnt(0)");
    }
    __builtin_amdgcn_s_barrier();
    __builtin_amdgcn_sched_barrier(0);
    const char* bufp = (const char*)&lds[cur][0];
    bf16x8 aF[4], bF[4];
#pragma unroll
    for (int n = 0; n < 4; ++n) bF[n] = *(const bf16x8*)(bufp + bOff[n]);
#pragma unroll
    for (int m = 0; m < 4; ++m) aF[m] = *(const bf16x8*)(bufp + aOff[m]);
    __builtin_amdgcn_s_setprio(1);
#pragma unroll
    for (int m = 0; m < 4; ++m)
#pragma unroll
      for (int n = 0; n < 4; ++n)
        acc[m][n] = __builtin_amdgcn_mfma_f32_16x16x32_bf16(aF[m], bF[n],
                                                            acc[m][n], 0, 0, 0);
    __builtin_amdgcn_s_setprio(0);
    __builtin_amdgcn_s_barrier();
  }
#undef STG2

  const int rbase = mt * 256 + wm * 64 + lhi * 4;
  const int cbase = nt * 128 + wn * 64 + frow;
#pragma unroll
  for (int n = 0; n < 4; ++n) {
    float bv = bias[cbase + n * 16];
#pragma unroll
    for (int m = 0; m < 4; ++m)
#pragma unroll
      for (int j = 0; j < 4; ++j)
        __builtin_nontemporal_store(acc[m][n][j] + bv,
            &C[(size_t)(rbase + m * 16 + j) * NBIG + cbase + n * 16]);
  }
}

// ---------------------------------------------------------------------------
// One-shot weight conversion: qw|kw|vw -> wqkvb (packed), ow -> wob,
// outw -> woutb.  Grid-stride over float4s with segment routing.
// ---------------------------------------------------------------------------
#define SEG (DIMN*DIMN/4)        // 262144 float4 per square weight
__global__ __launch_bounds__(256) void k_cvt5(
    const float* __restrict__ qw, const float* __restrict__ kw,
    const float* __restrict__ vw, const float* __restrict__ ow,
    const float* __restrict__ outw, ushort_t* __restrict__ wqkvb,
    ushort_t* __restrict__ wob, ushort_t* __restrict__ woutb) {
  const int total = 4 * SEG + (VOCABN * DIMN / 4);
  int idx = blockIdx.x * 256 + threadIdx.x;
  int stride = gridDim.x * 256;
  for (int i = idx; i < total; i += stride) {
    const float4* src; ushort4* dst;
    if (i < 3 * SEG) {
      src = (const float4*)(i < SEG ? qw : i < 2 * SEG ? kw : vw) +
            (i - (i < SEG ? 0 : i < 2 * SEG ? SEG : 2 * SEG));
      dst = (ushort4*)wqkvb + i;
    } else if (i < 4 * SEG) {
      src = (const float4*)ow + (i - 3 * SEG);
      dst = (ushort4*)wob + (i - 3 * SEG);
    } else {
      src = (const float4*)outw + (i - 4 * SEG);
      dst = (ushort4*)woutb + (i - 4 * SEG);
    }
    float4 v = *src;
    *dst = make_ushort4(f2bu(v.x), f2bu(v.y), f2bu(v.z), f2bu(v.w));
  }
}

// ctx[b,t] = sum_{o=0..3, t-o>=0} emb[x[b,t-o]]  -> bf16
__global__ __launch_bounds__(256) void k_embed(const int* __restrict__ x,
                                               const float* __restrict__ emb,
                                               ushort_t* __restrict__ ctxb) {
  const int t = blockIdx.x, b = blockIdx.y, tid = threadIdx.x;
  float4 s = make_float4(0.f, 0.f, 0.f, 0.f);
#pragma unroll
  for (int o = 0; o < 4; ++o) {
    if (t - o < 0) break;
    int tok = x[b * SEQN + t - o];
    float4 v = ((const float4*)(emb + (size_t)tok * DIMN))[tid];
    s.x += v.x; s.y += v.y; s.z += v.z; s.w += v.w;
  }
  ((ushort4*)(ctxb + ((size_t)(b * SEQN + t)) * DIMN))[tid] =
      make_ushort4(f2bu(s.x), f2bu(s.y), f2bu(s.z), f2bu(s.w));
}

// fused QKV: 1D grid 768 = 24 nt x 32 mt, XCD-chunked, m-fastest.
__global__ __launch_bounds__(256) void k_qkv(const ushort_t* __restrict__ A,
    const ushort_t* __restrict__ Bt, const float* __restrict__ qb2,
    const float* __restrict__ kb2, const float* __restrict__ vb2,
    ushort_t* __restrict__ Qb, ushort_t* __restrict__ Kb,
    ushort_t* __restrict__ Vb) {
  int l = blockIdx.x;
  int swz = (l & 7) * ((int)gridDim.x >> 3) + (l >> 3);  // 768 % 8 == 0
  const int mt = swz & 31;               // 32 m-tiles
  const int nt = swz >> 5;               // 0..23
  __shared__ __align__(16) ushort_t lA[128*64];
  __shared__ __align__(16) ushort_t lB[128*64];
  f32x4 acc[4][4] = {};
  const int tid = threadIdx.x;
  mma_core_s(A + (size_t)mt * 128 * KBIG,
             Bt + (size_t)nt * 128 * KBIG, KBIG, lA, lB, acc, tid);
  const int which = nt >> 3;             // 0:Q 1:K 2:V (wave-uniform)
  const int col0  = (nt & 7) * 128;
  ushort_t* Out = (which == 0) ? Qb : (which == 1) ? Kb : Vb;
  const float* Bv = (which == 0) ? qb2 : (which == 1) ? kb2 : vb2;
  const int lane = tid & 63, wr = (tid >> 7) & 1, wc = (tid >> 6) & 1;
  const int rbase = mt * 128 + wr * 64 + (lane >> 4) * 4;
  const int cbase = col0 + wc * 64 + (lane & 15);
#pragma unroll
  for (int m = 0; m < 4; ++m)
#pragma unroll
    for (int n = 0; n < 4; ++n) {
      int c = cbase + n * 16;
      float bv = Bv[c];
#pragma unroll
      for (int j = 0; j < 4; ++j)
        Out[(size_t)(rbase + m * 16 + j) * DIMN + c] = f2bu(acc[m][n][j] + bv);
    }
}

// o-proj: bf16 output (feeds LN)
__global__ __launch_bounds__(256) void k_oproj(const ushort_t* __restrict__ A,
    const ushort_t* __restrict__ Bt, const float* __restrict__ bias,
    ushort_t* __restrict__ C) {
  __shared__ __align__(16) ushort_t lA[128*64];
  __shared__ __align__(16) ushort_t lB[128*64];
  f32x4 acc[4][4] = {};
  const int tid = threadIdx.x;
  mma_core_s(A + (size_t)blockIdx.y * 128 * KBIG,
             Bt + (size_t)blockIdx.x * 128 * KBIG, KBIG, lA, lB, acc, tid);
  const int lane = tid & 63, wr = (tid >> 7) & 1, wc = (tid >> 6) & 1;
  const int rbase = blockIdx.y * 128 + wr * 64 + (lane >> 4) * 4;
  const int cbase = blockIdx.x * 128 + wc * 64 + (lane & 15);
#pragma unroll
  for (int m = 0; m < 4; ++m)
#pragma unroll
    for (int n = 0; n < 4; ++n) {
      int c = cbase + n * 16;
      float bv = bias[c];
#pragma unroll
      for (int j = 0; j < 4; ++j)
        C[(size_t)(rbase + m * 16 + j) * DIMN + c] = f2bu(acc[m][n][j] + bv);
    }
}

// transpose-gather V -> VgT[b][chunk]: [DIM][np] (zeros in pad)
__global__ __launch_bounds__(256) void k_transV(const ushort_t* __restrict__ Vb,
                                                ushort_t* __restrict__ VgT) {
  __shared__ ushort_t tile[64][66];
  const int z = blockIdx.z, b = z >> 3, i = z & 7;
  const int np = d_np[i], nk = d_nk[i], ko = d_koff[i];
  const int jb = blockIdx.x * 64;
  if (jb >= np) return;
  const int db = blockIdx.y * 64;
  const int tid = threadIdx.x, tx = tid & 63, ty = tid >> 6;
#pragma unroll
  for (int rep = 0; rep < 16; ++rep) {
    int jl = rep * 4 + ty;
    int j = jb + jl;
    ushort_t v = 0;
    if (j < nk) v = Vb[((size_t)b * SEQN + pos_of(i, j)) * DIMN + db + tx];
    tile[jl][tx] = v;
  }
  __syncthreads();
  const size_t base = ((size_t)b * ROWS_PB + ko) * DIMN;
#pragma unroll
  for (int rep = 0; rep < 16; ++rep) {
    int dl = rep * 4 + ty;
    VgT[base + (size_t)(db + dl) * np + jb + tx] = tile[tx][dl];
  }
}

// scores: P = exp(scale * Q K^T) with causal/pad mask -> bf16.
// K rows staged DIRECTLY from Kb via pos_of; per-row source pointers hoisted.
__global__ __launch_bounds__(256) void k_scores(const ushort_t* __restrict__ Qb,
    const ushort_t* __restrict__ Kb, ushort_t* __restrict__ P) {
  const int z = blockIdx.z, b = z >> 3, i = z & 7;
  const int np = d_np[i], nk = d_nk[i], ko = d_koff[i];
  if ((int)blockIdx.x * 128 >= np) return;
  __shared__ __align__(16) ushort_t lA[128*64];
  __shared__ __align__(16) ushort_t lB[128*64];
  f32x4 acc[4][4] = {};
  const int tid = threadIdx.x;
  const int lane = tid & 63, wr = (tid >> 7) & 1, wc = (tid >> 6) & 1;
  const int frow = lane & 15, lhi = lane >> 4;
  const int xk = (frow & 7) << 4;

  const char* sA[4]; const char* sB[4];
  {
    const char* Aq = (const char*)(Qb +
        ((size_t)(b * SEQN + i * CHUNKSZ) + blockIdx.y * 128) * DIMN);
#pragma unroll
    for (int t = 0; t < 4; ++t) {
      int cid = t * 256 + tid;
      int row = cid >> 3;                            // 0..127
      int srcoff = ((cid & 7) * 16) ^ ((row & 7) << 4);
      sA[t] = Aq + (size_t)row * 2048 + srcoff;
      int jg = blockIdx.x * 128 + row;               // gathered key index
      int pos = (jg < nk) ? pos_of(i, jg) : 0;       // pad -> row 0 (masked)
      sB[t] = (const char*)(Kb + ((size_t)b * SEQN + pos) * DIMN) + srcoff;
    }
  }

  for (int kt = 0; kt < KBIG; kt += 64) {
#pragma unroll
    for (int t = 0; t < 4; ++t) {
      int cid = t * 256 + tid;
      gload16(sA[t] + (size_t)kt * 2, (char*)lA + cid * 16);
      gload16(sB[t] + (size_t)kt * 2, (char*)lB + cid * 16);
    }
    __syncthreads();
#pragma unroll
    for (int kk = 0; kk < 2; ++kk) {
      bf16x8 af[4], bfr[4];
#pragma unroll
      for (int m = 0; m < 4; ++m) {
        int r = wr * 64 + m * 16 + frow;
        af[m] = *(const bf16x8*)((const char*)lA +
                 ((r * 128 + kk * 64 + lhi * 16) ^ xk));
      }
#pragma unroll
      for (int n = 0; n < 4; ++n) {
        int r = wc * 64 + n * 16 + frow;
        bfr[n] = *(const bf16x8*)((const char*)lB +
                  ((r * 128 + kk * 64 + lhi * 16) ^ xk));
      }
#pragma unroll
      for (int m = 0; m < 4; ++m)
#pragma unroll
        for (int n = 0; n < 4; ++n)
          acc[m][n] = __builtin_amdgcn_mfma_f32_16x16x32_bf16(af[m], bfr[n],
                                                              acc[m][n], 0, 0, 0);
    }
    __syncthreads();
  }

  const int rb = blockIdx.y * 128 + wr * 64 + (lane >> 4) * 4;
  const int cb = blockIdx.x * 128 + wc * 64 + (lane & 15);
  ushort_t* Pc = P + (size_t)b * PSTRIDE_B + (size_t)ko * 256;
  const float scale = 0.03125f;  // 1/sqrt(1024)
  const int diag0 = nk - CHUNKSZ;
#pragma unroll
  for (int m = 0; m < 4; ++m)
#pragma unroll
    for (int n = 0; n < 4; ++n) {
      int c = cb + n * 16;
#pragma unroll
      for (int j = 0; j < 4; ++j) {
        int r = rb + m * 16 + j;
        float w = 0.0f;
        if (c < nk && (c - diag0) <= r) w = expf(acc[m][n][j] * scale);
        Pc[(size_t)r * np + c] = f2bu(w);
      }
    }
}

// deterministic row sums of P (bf16 values, f32 accumulate)
__global__ __launch_bounds__(256) void k_rowsum(const ushort_t* __restrict__ P,
                                                float* __restrict__ rowsum) {
  const int z = blockIdx.y, b = z >> 3, i = z & 7, r = blockIdx.x;
  const int np = d_np[i], ko = d_koff[i];
  const ushort_t* row = P + (size_t)b * PSTRIDE_B + (size_t)ko * 256 + (size_t)r * np;
  const int tid = threadIdx.x;
  float s = 0.f;
  for (int c = tid; c < np; c += 256) s += b2f(row[c]);
#pragma unroll
  for (int o = 1; o < 64; o <<= 1) s += __shfl_xor(s, o);
  __shared__ float ss[4];
  if ((tid & 63) == 0) ss[tid >> 6] = s;
  __syncthreads();
  if (tid == 0) rowsum[z * 256 + r] = ss[0] + ss[1] + ss[2] + ss[3];
}

// attended = (P @ Vg) / rowsum -> bf16
__global__ __launch_bounds__(256) void k_pv(const ushort_t* __restrict__ P,
    const ushort_t* __restrict__ VgT, const float* __restrict__ rowsum,
    ushort_t* __restrict__ attb) {
  const int z = blockIdx.z, b = z >> 3, i = z & 7;
  const int np = d_np[i], ko = d_koff[i];
  __shared__ __align__(16) ushort_t lA[128*64];
  __shared__ __align__(16) ushort_t lB[128*64];
  f32x4 acc[4][4] = {};
  const int tid = threadIdx.x;
  const ushort_t* A  = P + (size_t)b * PSTRIDE_B + (size_t)ko * 256 +
                       (size_t)blockIdx.y * 128 * np;
  const ushort_t* Bt = VgT + ((size_t)b * ROWS_PB + ko) * DIMN +
                       (size_t)blockIdx.x * 128 * np;
  mma_core_s(A, Bt, np, lA, lB, acc, tid);
  const int lane = tid & 63, wr = (tid >> 7) & 1, wc = (tid >> 6) & 1;
  const int rb = blockIdx.y * 128 + wr * 64 + (lane >> 4) * 4;
  const int cb = blockIdx.x * 128 + wc * 64 + (lane & 15);
  const float* rs = rowsum + z * 256;
  ushort_t* outp = attb + (size_t)(b * SEQN + i * CHUNKSZ) * DIMN;
#pragma unroll
  for (int m = 0; m < 4; ++m)
#pragma unroll
    for (int j = 0; j < 4; ++j) {
      int r = rb + m * 16 + j;
      float inv = 1.0f / rs[r];
#pragma unroll
      for (int n = 0; n < 4; ++n)
        outp[(size_t)r * DIMN + cb + n * 16] = f2bu(acc[m][n][j] * inv);
    }
}

// LN over bf16 h -> bf16 hb
__global__ __launch_bounds__(256) void k_ln(const ushort_t* __restrict__ h,
    const float* __restrict__ lnw, const float* __restrict__ lnb,
    ushort_t* __restrict__ hb) {
  const int row = blockIdx.x, tid = threadIdx.x;
  ushort4 u4 = ((const ushort4*)(h + (size_t)row * DIMN))[tid];
  float4 v = make_float4(b2f(u4.x), b2f(u4.y), b2f(u4.z), b2f(u4.w));
  float s  = v.x + v.y + v.z + v.w;
  float sq = v.x * v.x + v.y * v.y + v.z * v.z + v.w * v.w;
#pragma unroll
  for (int o = 1; o < 64; o <<= 1) { s += __shfl_xor(s, o); sq += __shfl_xor(sq, o); }
  __shared__ float ss[4], ssq[4];
  if ((tid & 63) == 0) { ss[tid >> 6] = s; ssq[tid >> 6] = sq; }
  __syncthreads();
  s  = ss[0] + ss[1] + ss[2] + ss[3];
  sq = ssq[0] + ssq[1] + ssq[2] + ssq[3];
  const float mu  = s * (1.0f / DIMN);
  const float var = sq * (1.0f / DIMN) - mu * mu;
  const float inv = rsqrtf(var + LN_EPS);
  float4 w4 = ((const float4*)lnw)[tid];
  float4 b4 = ((const float4*)lnb)[tid];
  ushort4 o4 = make_ushort4(f2bu((v.x - mu) * inv * w4.x + b4.x),
                            f2bu((v.y - mu) * inv * w4.y + b4.y),
                            f2bu((v.z - mu) * inv * w4.z + b4.z),
                            f2bu((v.w - mu) * inv * w4.w + b4.w));
  ((ushort4*)(hb + (size_t)row * DIMN))[tid] = o4;
}

// ---------------------------------------------------------------------------
extern "C" void kernel_launch(void* const* d_in, const int* in_sizes, int n_in,
                              void* d_out, int out_size, void* d_ws, size_t ws_size,
                              hipStream_t stream) {
  const int*   x    = (const int*)  d_in[0];
  const float* emb  = (const float*)d_in[1];
  const float* qw   = (const float*)d_in[2];
  const float* qb   = (const float*)d_in[3];
  const float* kw   = (const float*)d_in[4];
  const float* kb   = (const float*)d_in[5];
  const float* vw   = (const float*)d_in[6];
  const float* vb   = (const float*)d_in[7];
  const float* ow   = (const float*)d_in[8];
  const float* ob   = (const float*)d_in[9];
  const float* lnw  = (const float*)d_in[10];
  const float* lnb  = (const float*)d_in[11];
  const float* outw = (const float*)d_in[12];
  const float* outb = (const float*)d_in[13];
  float* out = (float*)d_out;
  (void)in_sizes; (void)n_in; (void)out_size; (void)ws_size;

  char* ws = (char*)d_ws;
  size_t off = 0;
  auto alloc = [&](size_t bytes) {
    size_t r = off; off += (bytes + 255) & ~(size_t)255; return r;
  };
  ushort_t* wqkvb = (ushort_t*)(ws + alloc((size_t)3 * DIMN * DIMN * 2));
  ushort_t* wob   = (ushort_t*)(ws + alloc((size_t)DIMN * DIMN * 2));
  ushort_t* woutb = (ushort_t*)(ws + alloc((size_t)VOCABN * DIMN * 2));
  ushort_t* ctxb  = (ushort_t*)(ws + alloc((size_t)BATCHN * SEQN * DIMN * 2));
  ushort_t* Qb    = (ushort_t*)(ws + alloc((size_t)BATCHN * SEQN * DIMN * 2));
  ushort_t* Kb    = (ushort_t*)(ws + alloc((size_t)BATCHN * SEQN * DIMN * 2));
  ushort_t* Vb    = (ushort_t*)(ws + alloc((size_t)BATCHN * SEQN * DIMN * 2));
  ushort_t* VgT   = (ushort_t*)(ws + alloc((size_t)BATCHN * ROWS_PB * DIMN * 2));
  ushort_t* Pm    = (ushort_t*)(ws + alloc((size_t)BATCHN * PSTRIDE_B * 2));
  float*    rsum  = (float*)   (ws + alloc((size_t)BATCHN * NCHUNK * 256 * 4));
  ushort_t* attb  = (ushort_t*)(ws + alloc((size_t)BATCHN * SEQN * DIMN * 2));
  ushort_t* hbuf  = (ushort_t*)(ws + alloc((size_t)BATCHN * SEQN * DIMN * 2));
  ushort_t* hb    = (ushort_t*)(ws + alloc((size_t)BATCHN * SEQN * DIMN * 2));

  // all weight conversions in one launch
  k_cvt5<<<dim3(4096), dim3(256), 0, stream>>>(qw, kw, vw, ow, outw,
                                               wqkvb, wob, woutb);

  // embedding + 4-tap context sum
  k_embed<<<dim3(SEQN, BATCHN), dim3(256), 0, stream>>>(x, emb, ctxb);

  // fused QKV projection (768 blocks, XCD-chunked)
  k_qkv<<<dim3(768), dim3(256), 0, stream>>>(ctxb, wqkvb, qb, kb, vb,
                                             Qb, Kb, Vb);

  // V transpose-gather (K gather folded into k_scores)
  k_transV<<<dim3(14, 16, BATCHN * NCHUNK), dim3(256), 0, stream>>>(Vb, VgT);

  // attention
  k_scores<<<dim3(7, 2, BATCHN * NCHUNK), dim3(256), 0, stream>>>(Qb, Kb, Pm);
  k_rowsum<<<dim3(256, BATCHN * NCHUNK), dim3(256), 0, stream>>>(Pm, rsum);
  k_pv<<<dim3(8, 2, BATCHN * NCHUNK), dim3(256), 0, stream>>>(Pm, VgT, rsum, attb);

  // output projection (bf16 out) + layernorm (bf16 in)
  k_oproj<<<dim3(8, 32), dim3(256), 0, stream>>>(attb, wob, ob, hbuf);
  k_ln<<<dim3(BATCHN * SEQN), dim3(256), 0, stream>>>(hbuf, lnw, lnb, hb);

  // vocab projection: r15-exact 256x128 / BK=32 / 2-blocks-per-CU kernel
  k_vocab2<<<dim3(4000), dim3(512), 0, stream>>>(hb, woutb, outb, out);
}